// Round 7
// baseline (224.135 us; speedup 1.0000x reference)
//
#include <hip/hip_runtime.h>
#include <math.h>

// Each 16-byte vector holds two consecutive 2-d states: (x0,y0,x1,y1).
// out = (C*x + S*y, -S*x + C*y) where [C,S] is the exact composite of the
// 1000 float32-rounded rotation steps, computed in double on the host.
//
// NOTE: HIP's float4 is HIP_vector_type<float,4> (a class) and is NOT a
// valid operand for __builtin_nontemporal_load/store. Use a raw clang
// ext_vector_type(4) typedef instead — same 16-byte layout/alignment.
//
// nt load/store: both streams touched exactly once -> bypass L2 allocation
// (measured +2-5 us total in R6 vs baseline).
//
// Grid-stride with capped grid (2048 wg = 256 CU x 8): each thread does 16
// iterations; #pragma unroll 4 gives 4 independent nt loads in flight per
// thread (vs 1 in the one-shot version) and amortizes wave launch/retire.
typedef float f32x4 __attribute__((ext_vector_type(4)));

__global__ __launch_bounds__(256) void lin2d_rot_kernel(
    const f32x4* __restrict__ in, f32x4* __restrict__ out,
    int n4, float C, float S) {
    const int stride = gridDim.x * blockDim.x;
    #pragma unroll 4
    for (int i = blockIdx.x * blockDim.x + threadIdx.x; i < n4; i += stride) {
        f32x4 v = __builtin_nontemporal_load(in + i);
        f32x4 r;
        // Expression forms identical to the passing kernel so fp-contraction
        // (and thus absmax) is unchanged.
        r.x =  C * v.x + S * v.y;
        r.y = -S * v.x + C * v.y;
        r.z =  C * v.z + S * v.w;
        r.w = -S * v.z + C * v.w;
        __builtin_nontemporal_store(r, out + i);
    }
}

extern "C" void kernel_launch(void* const* d_in, const int* in_sizes, int n_in,
                              void* d_out, int out_size, void* d_ws, size_t ws_size,
                              hipStream_t stream) {
    (void)d_ws; (void)ws_size; (void)n_in; (void)out_size;

    // Reproduce the float32-rounded per-step constants, then compose exactly
    // in double: M = [[c,s],[-s,c]] acting on column (x0,x1) per step.
    // M^1000 = r^1000 * [[cos(1000*phi), sin(1000*phi)], [-sin, cos]].
    const double theta = M_PI / 100.0;
    const float cf = (float)cos(theta);
    const float sf = (float)sin(theta);
    const double r   = sqrt((double)cf * cf + (double)sf * sf);
    const double phi = atan2((double)sf, (double)cf);
    const double scale = pow(r, 1000.0);
    const double ang   = 1000.0 * phi;
    const float C = (float)(scale * cos(ang));
    const float S = (float)(scale * sin(ang));

    const f32x4* in  = (const f32x4*)d_in[0];
    f32x4*       out = (f32x4*)d_out;
    const int n_elems = in_sizes[0];      // 16777216 * 2 floats
    const int n4 = n_elems / 4;           // two states per 16B vector

    const int block = 256;
    // Memory-bound: cap the grid and grid-stride (Guideline 11).
    // 2048 = 256 CUs x 8 workgroups/CU; n4 = 8388608 -> 16 iters/thread.
    int grid = (n4 + block - 1) / block;
    if (grid > 2048) grid = 2048;
    lin2d_rot_kernel<<<grid, block, 0, stream>>>(in, out, n4, C, S);
}

// Round 8
// 222.325 us; speedup vs baseline: 1.0081x; 1.0081x over previous
//
#include <hip/hip_runtime.h>
#include <math.h>

// Each 32-byte vector holds four consecutive 2-d states:
// (x0,y0,x1,y1,x2,y2,x3,y3).
// out = (C*x + S*y, -S*x + C*y) per pair, where [C,S] is the exact
// composite of the 1000 float32-rounded rotation steps (host, double).
//
// R6 lesson: nt one-shot at 16B/thread = 215.9 us (best). R7 lesson:
// grid-stride loop REGRESSED (224 us) — loop overhead on the load path,
// TLP was already sufficient. This round: keep the one-shot structure,
// widen to 32B/thread (ext_vector_type(8) -> two independent nt
// global_load_dwordx4 per thread) for 2x memory-level parallelism per
// lane and half the wave launch/retire count, with zero loop overhead.
//
// NOTE: HIP's float4 is a class, invalid for __builtin_nontemporal_*;
// raw clang ext_vector_type is required.
typedef float f32x8 __attribute__((ext_vector_type(8)));

__global__ __launch_bounds__(256) void lin2d_rot_kernel(
    const f32x8* __restrict__ in, f32x8* __restrict__ out,
    int n8, float C, float S) {
    int i = blockIdx.x * blockDim.x + threadIdx.x;
    if (i < n8) {
        f32x8 v = __builtin_nontemporal_load(in + i);
        f32x8 r;
        // Same per-pair expression forms as the passing kernels so
        // fp-contraction (and thus absmax) is unchanged.
        r[0] =  C * v[0] + S * v[1];
        r[1] = -S * v[0] + C * v[1];
        r[2] =  C * v[2] + S * v[3];
        r[3] = -S * v[2] + C * v[3];
        r[4] =  C * v[4] + S * v[5];
        r[5] = -S * v[4] + C * v[5];
        r[6] =  C * v[6] + S * v[7];
        r[7] = -S * v[6] + C * v[7];
        __builtin_nontemporal_store(r, out + i);
    }
}

extern "C" void kernel_launch(void* const* d_in, const int* in_sizes, int n_in,
                              void* d_out, int out_size, void* d_ws, size_t ws_size,
                              hipStream_t stream) {
    (void)d_ws; (void)ws_size; (void)n_in; (void)out_size;

    // Reproduce the float32-rounded per-step constants, then compose exactly
    // in double: M = [[c,s],[-s,c]] acting on column (x0,x1) per step.
    // M^1000 = r^1000 * [[cos(1000*phi), sin(1000*phi)], [-sin, cos]].
    const double theta = M_PI / 100.0;
    const float cf = (float)cos(theta);
    const float sf = (float)sin(theta);
    const double r   = sqrt((double)cf * cf + (double)sf * sf);
    const double phi = atan2((double)sf, (double)cf);
    const double scale = pow(r, 1000.0);
    const double ang   = 1000.0 * phi;
    const float C = (float)(scale * cos(ang));
    const float S = (float)(scale * sin(ang));

    const f32x8* in  = (const f32x8*)d_in[0];
    f32x8*       out = (f32x8*)d_out;
    const int n_elems = in_sizes[0];      // 16777216 * 2 floats
    const int n8 = n_elems / 8;           // four states per 32B vector

    const int block = 256;
    const int grid = (n8 + block - 1) / block;   // 16384 workgroups
    lin2d_rot_kernel<<<grid, block, 0, stream>>>(in, out, n8, C, S);
}

// Round 9
// 217.219 us; speedup vs baseline: 1.0318x; 1.0235x over previous
//
#include <hip/hip_runtime.h>
#include <math.h>

// Each 16-byte vector holds two consecutive 2-d states: (x0,y0,x1,y1).
// out = (C*x + S*y, -S*x + C*y) where [C,S] is the exact composite of the
// 1000 float32-rounded rotation steps, computed in double on the host.
//
// NOTE: HIP's float4 is HIP_vector_type<float,4> (a class) and is NOT a
// valid operand for __builtin_nontemporal_load/store. Use a raw clang
// ext_vector_type(4) typedef instead — same 16-byte layout/alignment.
//
// Both streams are touched exactly once -> non-temporal load/store ('nt'
// flag on global_load/store_dwordx4) bypasses L2 allocation, so the 128 MB
// write stream's write-allocate lines don't evict the read stream from the
// 4 MiB-per-XCD L2s.
//
// Session ladder: baseline 218.0/221.5 -> nt one-shot 215.9 (BEST, this
// source) -> grid-stride 224.1 (REGRESSED: loop overhead, TLP sufficient)
// -> 32B/thread 222.3 (REGRESSED: MLP not the limiter). One-shot 16B/lane
// nt is the measured optimum for this compulsory-traffic stream.
typedef float f32x4 __attribute__((ext_vector_type(4)));

__global__ __launch_bounds__(256) void lin2d_rot_kernel(
    const f32x4* __restrict__ in, f32x4* __restrict__ out,
    int n4, float C, float S) {
    int i = blockIdx.x * blockDim.x + threadIdx.x;
    if (i < n4) {
        f32x4 v = __builtin_nontemporal_load(in + i);
        f32x4 r;
        // Expression forms identical to the passing kernel so fp-contraction
        // (and thus absmax) is unchanged.
        r.x =  C * v.x + S * v.y;
        r.y = -S * v.x + C * v.y;
        r.z =  C * v.z + S * v.w;
        r.w = -S * v.z + C * v.w;
        __builtin_nontemporal_store(r, out + i);
    }
}

extern "C" void kernel_launch(void* const* d_in, const int* in_sizes, int n_in,
                              void* d_out, int out_size, void* d_ws, size_t ws_size,
                              hipStream_t stream) {
    (void)d_ws; (void)ws_size; (void)n_in; (void)out_size;

    // Reproduce the float32-rounded per-step constants, then compose exactly
    // in double: M = [[c,s],[-s,c]] acting on column (x0,x1) per step.
    // M^1000 = r^1000 * [[cos(1000*phi), sin(1000*phi)], [-sin, cos]].
    const double theta = M_PI / 100.0;
    const float cf = (float)cos(theta);
    const float sf = (float)sin(theta);
    const double r   = sqrt((double)cf * cf + (double)sf * sf);
    const double phi = atan2((double)sf, (double)cf);
    const double scale = pow(r, 1000.0);
    const double ang   = 1000.0 * phi;
    const float C = (float)(scale * cos(ang));
    const float S = (float)(scale * sin(ang));

    const f32x4* in  = (const f32x4*)d_in[0];
    f32x4*       out = (f32x4*)d_out;
    const int n_elems = in_sizes[0];      // 16777216 * 2 floats
    const int n4 = n_elems / 4;           // two states per 16B vector

    const int block = 256;
    const int grid = (n4 + block - 1) / block;
    lin2d_rot_kernel<<<grid, block, 0, stream>>>(in, out, n4, C, S);
}